// Round 2
// 1363.696 us; speedup vs baseline: 1.0137x; 1.0137x over previous
//
#include <hip/hip_runtime.h>

// RegressiveAutoEncoder B=2048,T=512,F=8,H=128 — MFMA v6b.
// v5 + latency surgery on the 1024-step serial loop:
//  (1) lgkm-only barrier (raw s_barrier; no vmcnt/expcnt drain -> decoder
//      out-store acks and encoder x-loads no longer serialize at the barrier)
//  (2) xp/xq rows padded 32->40 shorts (80B): kills the 8-way bank conflict
//      on the A[4] ds_read_b128 (word stride 20 covers all 8 bank groups)
//  (3) encoder x staged in 16-step pre-split chunks (xq dbuf); global load
//      issued at t%16==14, LDS write at t%16==15 -> ~1.5 steps (~4500 cy)
//      load->use distance, fully covering the ~900 cy cold HBM miss
//  (4) shfl_xor(32) folds -> v_permlane32_swap (VALU, no LDS pipe)
//  (5) MFMA chain split 5 -> 3+2 (8 independent chains)
//  (6) W OOB read for kk>=16 clamped to 0 (A rows are zero there)

namespace {

typedef __attribute__((ext_vector_type(8))) short bf16x8;
typedef __attribute__((ext_vector_type(4))) float f32x4;
typedef __attribute__((ext_vector_type(2))) unsigned int uint2v;
typedef __attribute__((ext_vector_type(4))) unsigned int uint4v;
typedef __attribute__((ext_vector_type(2))) unsigned short ushort2v;
typedef __attribute__((ext_vector_type(2))) float float2v;

constexpr int T = 512, F = 8, H = 128, G4 = 512, NTH = 512;
constexpr int HS = 136;  // hb row stride in shorts (272B, b128-aligned)
constexpr int XS = 40;   // xp/xq row stride in shorts (80B): conflict-free reads
constexpr int CS = 16;   // encoder x chunk length (timesteps)

struct __align__(16) Smem {
  unsigned short hb[2][16][HS];      // rows 0..7 h_hi, 8..15 h_lo; dbuf by parity
  unsigned short xp[2][16][XS];      // decoder feedback y; dbuf by parity
  unsigned short xq[2][CS][16][XS];  // encoder pre-split x chunks; dbuf by chunk
};

__device__ __forceinline__ float rcpf(float v) { return __builtin_amdgcn_rcpf(v); }
__device__ __forceinline__ float sigm(float v) { return rcpf(1.0f + __expf(-v)); }
__device__ __forceinline__ float tanh_(float v) { return 1.0f - 2.0f * rcpf(__expf(2.0f * v) + 1.0f); }

__device__ __forceinline__ unsigned short bf_rtn(float v) {
  unsigned u = __float_as_uint(v);
  return (unsigned short)((u + 0x7FFFu + ((u >> 16) & 1u)) >> 16);
}
__device__ __forceinline__ void split_tr(float v, unsigned short& hi, unsigned short& lo) {
  unsigned u = __float_as_uint(v);
  hi = (unsigned short)(u >> 16);
  lo = bf_rtn(v - __uint_as_float(u & 0xFFFF0000u));
}

// v[lane] + v[lane^32] broadcast to all lanes: 1 permlane + 1 add, no LDS.
// new_vdst[i] = v[i<32 ? i : i-32]; new_vsrc[i] = v[i<32 ? i+32 : i]
// -> r[0]+r[1] = v[i]+v[i^32] on every lane (order-independent, fp-commutative).
__device__ __forceinline__ float fold32(float v) {
  unsigned u = __float_as_uint(v);
  uint2v r = __builtin_amdgcn_permlane32_swap(u, u, false, false);
  return __uint_as_float(r[0]) + __uint_as_float(r[1]);
}

// Barrier draining only LDS (lgkm). Outstanding global stores/loads (vmcnt,
// expcnt) are NOT drained -- the compiler still inserts waits at actual uses.
__device__ __forceinline__ void bar_lgkm() {
  __asm__ __volatile__("s_waitcnt lgkmcnt(0)" ::: "memory");
  __builtin_amdgcn_s_barrier();
  __asm__ __volatile__("" ::: "memory");
}

__global__ __launch_bounds__(NTH, 2)
void rae_v6b(const float* __restrict__ x,
             const float* __restrict__ Wenc, const float* __restrict__ Uenc, const float* __restrict__ benc,
             const float* __restrict__ Wdec, const float* __restrict__ Udec, const float* __restrict__ bdec,
             const float* __restrict__ Wout, const float* __restrict__ boutg,
             float* __restrict__ out)
{
  __shared__ Smem s;
  const int tid = threadIdx.x, lane = tid & 63, w = tid >> 6;
  const int q = lane >> 4, n = lane & 15;
  const long gb = (long)blockIdx.x * 8;

  {  // vectorized zero of all LDS (zeros double as the K-padding regions)
    uint4v z4 = {0u, 0u, 0u, 0u};
#pragma unroll 4
    for (int i = tid; i < (int)(sizeof(Smem) / 16); i += NTH)
      ((uint4v*)&s)[i] = z4;
  }
  __syncthreads();

  // encoder x staging decomposition: 512 thr = 8 rows x 16 steps x 4 float2
  const int sr = tid >> 6, sts = (tid >> 2) & 15, sfp = tid & 3;
  const long xsb = (gb + sr) * (long)(T * F) + sts * F + sfp * 2;

  {  // stage chunk 0 (steps 0..15)
    float2v xv0 = *(const float2v*)&x[xsb];
    unsigned short h0s, l0s, h1s, l1s;
    split_tr(xv0[0], h0s, l0s); split_tr(xv0[1], h1s, l1s);
    ushort2v hh = {h0s, h1s}, ll = {l0s, l1s};
    *(ushort2v*)&s.xq[0][sts][sr][sfp * 2] = hh;
    *(ushort2v*)&s.xq[0][sts][sr + 8][sfp * 2] = ll;
    *(ushort2v*)&s.xq[0][sts][sr + 8][8 + sfp * 2] = hh;
  }

  // Wout fragments: N-cols 0..7 = Wout_hi, 8..15 = Wout_lo
  bf16x8 Bw[4];
#pragma unroll
  for (int kt = 0; kt < 4; ++kt) {
    bf16x8 bw;
#pragma unroll
    for (int j = 0; j < 8; ++j) {
      unsigned short hv, lv; split_tr(Wout[(kt * 32 + q * 8 + j) * F + (n & 7)], hv, lv);
      bw[j] = (short)((n < 8) ? hv : lv);
    }
    Bw[kt] = bw;
  }
  const float boutr = boutg[n & 7];
  float cst[2] = {0.f, 0.f};
  __syncthreads();

  bf16x8 A[5];
  {
    bf16x8 zz = {0, 0, 0, 0, 0, 0, 0, 0};
#pragma unroll
    for (int kt = 0; kt < 5; ++kt) A[kt] = zz;
  }

  bf16x8 B1[5][4];
  float brg2[4];

  for (int ph = 0; ph < 2; ++ph) {
    const float* U  = ph ? Udec : Uenc;
    const float* W  = ph ? Wdec : Wenc;
    const float* bi = ph ? bdec : benc;

    // B preload: kt<4 = rtn-bf16(U); kt=4: kk<8 -> W_hi, kk in 8..15 -> W_lo,
    // kk>=16 -> 0 (matching zero A rows)
#pragma unroll
    for (int kt = 0; kt < 5; ++kt)
#pragma unroll
      for (int g = 0; g < 4; ++g) {
        const int col = g * 128 + w * 16 + n;
        bf16x8 b1;
#pragma unroll
        for (int j = 0; j < 8; ++j) {
          unsigned short v = 0;
          if (kt < 4) {
            v = bf_rtn(U[(kt * 32 + q * 8 + j) * G4 + col]);
          } else {
            const int kk = q * 8 + j;
            unsigned short hv, lv;
            if (kk < 8)       { split_tr(W[kk * G4 + col], hv, lv); v = hv; }
            else if (kk < 16) { split_tr(W[(kk - 8) * G4 + col], hv, lv); v = lv; }
          }
          b1[j] = (short)v;
        }
        B1[kt][g] = b1;
      }
#pragma unroll
    for (int g = 0; g < 4; ++g) brg2[g] = 0.5f * bi[g * 128 + w * 16 + n];

    if (ph == 1) {  // stage y_{-1} = x[:,T-1,:] into parity slot 0
      if (tid < 64) {
        unsigned short hv, lv;
        split_tr(x[(gb + (tid >> 3)) * (long)(T * F) + (T - 1) * F + (tid & 7)], hv, lv);
        s.xp[0][tid >> 3][tid & 7] = hv;
        s.xp[0][(tid >> 3) + 8][tid & 7] = lv;
        s.xp[0][(tid >> 3) + 8][(tid & 7) + 8] = hv;
      }
      __syncthreads();
    }

    float2v xv = {0.f, 0.f};  // in-flight next-chunk x (held across 1 step)

    for (int t = 0; t < T; ++t) {
      const int pcur = t & 1, pnxt = pcur ^ 1;

      A[4] = (ph == 0)
           ? *(const bf16x8*)&s.xq[(t >> 4) & 1][t & (CS - 1)][n][q * 8]
           : *(const bf16x8*)&s.xp[pcur][n][q * 8];

      // issue next-chunk loads ~1.5 steps before LDS write/use
      const bool do_load  = (ph == 0) && (((t + 2) & (CS - 1)) == 0) && (t + 2 < T);
      const bool do_write = (ph == 0) && (((t + 1) & (CS - 1)) == 0) && (t + 1 < T);
      if (do_load) xv = *(const float2v*)&x[xsb + (long)(t + 2) * F];

      // ---- MFMA pass: 5 ksteps x 4 gates, split 3+2 chains ----
      f32x4 acc[4], acc2[4];
#pragma unroll
      for (int g = 0; g < 4; ++g) {
        acc[g]  = f32x4{brg2[g], brg2[g], brg2[g], brg2[g]};
        acc2[g] = f32x4{0.f, 0.f, 0.f, 0.f};
      }
#pragma unroll
      for (int kt = 0; kt < 3; ++kt)
#pragma unroll
        for (int g = 0; g < 4; ++g)
          acc[g] = __builtin_amdgcn_mfma_f32_16x16x32_bf16(A[kt], B1[kt][g], acc[g], 0, 0, 0);
#pragma unroll
      for (int kt = 3; kt < 5; ++kt)
#pragma unroll
        for (int g = 0; g < 4; ++g)
          acc2[g] = __builtin_amdgcn_mfma_f32_16x16x32_bf16(A[kt], B1[kt][g], acc2[g], 0, 0, 0);

      // ---- fuse hi/lo rows via permlane32_swap (no LDS pipe) ----
      float zA[4], zB[4];
#pragma unroll
      for (int g = 0; g < 4; ++g) {
        const float f0 = fold32(acc[g][0] + acc2[g][0]);
        const float f1 = fold32(acc[g][1] + acc2[g][1]);
        const float f2 = fold32(acc[g][2] + acc2[g][2]);
        const float f3 = fold32(acc[g][3] + acc2[g][3]);
        zA[g] = (lane < 32) ? f0 : f2;
        zB[g] = (lane < 32) ? f1 : f3;
      }
      const int r0 = ((lane & 31) >> 4) * 4 + ((lane < 32) ? 0 : 2);
      const int cc = w * 16 + n;
      cst[0] = sigm(zA[1]) * cst[0] + sigm(zA[0]) * tanh_(zA[2]);
      cst[1] = sigm(zB[1]) * cst[1] + sigm(zB[0]) * tanh_(zB[2]);
      const float h0 = sigm(zA[3]) * tanh_(cst[0]);
      const float h1 = sigm(zB[3]) * tanh_(cst[1]);
      {
        unsigned short hv0, lv0, hv1, lv1;
        split_tr(h0, hv0, lv0); split_tr(h1, hv1, lv1);
        s.hb[pnxt][r0][cc]     = hv0;  s.hb[pnxt][r0 + 8][cc] = lv0;
        s.hb[pnxt][r0 + 1][cc] = hv1;  s.hb[pnxt][r0 + 9][cc] = lv1;
      }

      if (do_write) {  // write pre-split next chunk into the other xq buffer
        const int cb = ((t + 1) >> 4) & 1;
        unsigned short h0s, l0s, h1s, l1s;
        split_tr(xv[0], h0s, l0s); split_tr(xv[1], h1s, l1s);
        ushort2v hh = {h0s, h1s}, ll = {l0s, l1s};
        *(ushort2v*)&s.xq[cb][sts][sr][sfp * 2] = hh;
        *(ushort2v*)&s.xq[cb][sts][sr + 8][sfp * 2] = ll;
        *(ushort2v*)&s.xq[cb][sts][sr + 8][8 + sfp * 2] = hh;
      }

      bar_lgkm();   // lgkm-only: out-stores / x-loads never drain here

      // h fragments for next iter / dense (rows 0..15 incl. lo-rows)
#pragma unroll
      for (int kt = 0; kt < 4; ++kt)
        A[kt] = *(const bf16x8*)&s.hb[pnxt][n][kt * 32 + q * 8];

      if (ph == 1) {
        // dense y = relu(h@Wout + b), redundant per wave
        f32x4 ay = {0.f, 0.f, 0.f, 0.f};
#pragma unroll
        for (int kt = 0; kt < 4; ++kt)
          ay = __builtin_amdgcn_mfma_f32_16x16x32_bf16(A[kt], Bw[kt], ay, 0, 0, 0);
        float y[4];
#pragma unroll
        for (int p = 0; p < 4; ++p) {
          const float s8  = ay[p] + __shfl_xor(ay[p], 8, 64);  // + h@Wout_lo
          const float s32 = fold32(s8);                        // + h_lo@Wout
          y[p] = fmaxf(s32 + boutr, 0.f);
        }
        if (q < 2 && n < 8) {                                  // rows q*4+p, col f=n
          const int rr = q * 4;
          if (w == 0) {
#pragma unroll
            for (int p = 0; p < 4; ++p)
              out[((gb + rr + p) * T + t) * F + n] = y[p];
          }
#pragma unroll
          for (int p = 0; p < 4; ++p) {                        // idempotent feedback
            unsigned short hv, lv; split_tr(y[p], hv, lv);
            s.xp[pnxt][rr + p][n]         = hv;
            s.xp[pnxt][rr + p + 8][n]     = lv;
            s.xp[pnxt][rr + p + 8][n + 8] = hv;
          }
        }
      }
    }
  }
}

} // namespace

extern "C" void kernel_launch(void* const* d_in, const int* in_sizes, int n_in,
                              void* d_out, int out_size, void* d_ws, size_t ws_size,
                              hipStream_t stream) {
  const float* x    = (const float*)d_in[0];
  const float* Wenc = (const float*)d_in[1];
  const float* Uenc = (const float*)d_in[2];
  const float* benc = (const float*)d_in[3];
  const float* Wdec = (const float*)d_in[4];
  const float* Udec = (const float*)d_in[5];
  const float* bdec = (const float*)d_in[6];
  const float* Wout = (const float*)d_in[7];
  const float* bout = (const float*)d_in[8];
  float* out = (float*)d_out;

  const int Bsz = in_sizes[0] / (T * F);  // 2048
  const int nblocks = Bsz / 8;            // 256
  rae_v6b<<<dim3(nblocks), dim3(NTH), 0, stream>>>(
      x, Wenc, Uenc, benc, Wdec, Udec, bdec, Wout, bout, out);
}

// Round 4
// 1058.959 us; speedup vs baseline: 1.3054x; 1.2878x over previous
//
#include <hip/hip_runtime.h>

// RegressiveAutoEncoder B=2048,T=512,F=8,H=128 — MFMA v7b (issue-count diet, fixed).
// v7 failed: xv (in-flight x chunk) was scoped inside the t-loop, so the
// load@t+2 / write@t+1 split wrote zeros. v7b hoists xv out (as in v6b).
// Also: pair_fold's permlane32_swap convention is probed once at init and
// folded into r0, making the kernel correct under either swap direction.
// Changes vs v6b (all issue-count reductions; v6b measured VALU 59.8% +
// MFMA 23.1% at 2 waves/SIMD -> SIMD issue-bound):
//  (1) hi/lo M-fold via TWO-OPERAND permlane32_swap(c_p, c_{p+2}): one swap
//      + one add yields z on all lanes (56 -> 16 VALU per step per wave)
//  (2) bias4[g] passed as MFMA C-operand: acc init movs 32 -> 0; single
//      5-deep chain (acc2 removed)
//  (3) decoder epilogue: pair-swap puts y rows r0,r0+1 in each lane ->
//      2 splits / 2 out stores / 6 feedback writes (was 4/4/12)
//  (4) x-chunk staging re-decomposed (srow in lane bits 2..4): write stride
//      no longer =0 mod 32 banks (was 16-way conflict)
//  (5) enc/dec split into separate loops; sync between LDS zero and stage
// Kept: lgkm-only barrier, padded XS=40 rows, 16-step x chunks with
// load@t+2 / write@t+1, rtn-bf16 U single term, 3-term x/y via
// [x_hi|0]/[x_lo|x_hi] rows, 0.5x bias (rows counted twice).

namespace {

typedef __attribute__((ext_vector_type(8))) short bf16x8;
typedef __attribute__((ext_vector_type(4))) float f32x4;
typedef __attribute__((ext_vector_type(2))) unsigned int uint2v;
typedef __attribute__((ext_vector_type(4))) unsigned int uint4v;
typedef __attribute__((ext_vector_type(2))) unsigned short ushort2v;
typedef __attribute__((ext_vector_type(2))) float float2v;

constexpr int T = 512, F = 8, H = 128, G4 = 512, NTH = 512;
constexpr int HS = 136;  // hb row stride in shorts (272B, b128-aligned)
constexpr int XS = 40;   // xp/xq row stride in shorts (80B)
constexpr int CS = 16;   // encoder x chunk length (timesteps)

struct __align__(16) Smem {
  unsigned short hb[2][16][HS];      // rows 0..7 h_hi, 8..15 h_lo; dbuf by parity
  unsigned short xp[2][16][XS];      // decoder feedback y; dbuf by parity
  unsigned short xq[2][CS][16][XS];  // encoder pre-split x chunks; dbuf by chunk
};

__device__ __forceinline__ float rcpf(float v) { return __builtin_amdgcn_rcpf(v); }
__device__ __forceinline__ float sigm(float v) { return rcpf(1.0f + __expf(-v)); }
__device__ __forceinline__ float tanh_(float v) { return 1.0f - 2.0f * rcpf(__expf(2.0f * v) + 1.0f); }

__device__ __forceinline__ unsigned short bf_rtn(float v) {
  unsigned u = __float_as_uint(v);
  return (unsigned short)((u + 0x7FFFu + ((u >> 16) & 1u)) >> 16);
}
__device__ __forceinline__ void split_tr(float v, unsigned short& hi, unsigned short& lo) {
  unsigned u = __float_as_uint(v);
  hi = (unsigned short)(u >> 16);
  lo = bf_rtn(v - __uint_as_float(u & 0xFFFF0000u));
}

// Pair-fold: returns on one 32-lane half fold(a)=a[l]+a[l^32], on the other
// half fold(b). WHICH half gets a vs b depends on the permlane32_swap
// convention; the caller probes it once (pair_fold(0,1) -> 0 on a-fold
// lanes, 2 on b-fold lanes) and bakes it into the row assignment r0.
__device__ __forceinline__ float pair_fold(float a, float b) {
  uint2v r = __builtin_amdgcn_permlane32_swap(__float_as_uint(a), __float_as_uint(b), false, false);
  return __uint_as_float(r[0]) + __uint_as_float(r[1]);
}

// Barrier draining only LDS (lgkm); outstanding global ops not drained.
__device__ __forceinline__ void bar_lgkm() {
  __asm__ __volatile__("s_waitcnt lgkmcnt(0)" ::: "memory");
  __builtin_amdgcn_s_barrier();
  __asm__ __volatile__("" ::: "memory");
}

__global__ __launch_bounds__(NTH, 2)
void rae_v7b(const float* __restrict__ x,
             const float* __restrict__ Wenc, const float* __restrict__ Uenc, const float* __restrict__ benc,
             const float* __restrict__ Wdec, const float* __restrict__ Udec, const float* __restrict__ bdec,
             const float* __restrict__ Wout, const float* __restrict__ boutg,
             float* __restrict__ out)
{
  __shared__ Smem s;
  const int tid = threadIdx.x, lane = tid & 63, w = tid >> 6;
  const int q = lane >> 4, n = lane & 15;
  const long gb = (long)blockIdx.x * 8;

  {  // vectorized zero of all LDS (zeros double as the K-padding regions)
    uint4v z4 = {0u, 0u, 0u, 0u};
#pragma unroll 4
    for (int i = tid; i < (int)(sizeof(Smem) / 16); i += NTH)
      ((uint4v*)&s)[i] = z4;
  }
  __syncthreads();  // zero pass must complete before any staging

  // encoder x staging: 512 thr = 16 steps x 8 rows x 4 float2.
  // srow in lane bits 2..4 -> write banks (20*srow + sfp) mod 32 cover all
  // 32 banks across a half-wave (2-way across sts parity: free).
  const int sfp = tid & 3, srow = (tid >> 2) & 7, sts = tid >> 5;
  const long xsb = (gb + srow) * (long)(T * F) + sts * F + sfp * 2;

  {  // stage chunk 0 (steps 0..15)
    float2v xv0 = *(const float2v*)&x[xsb];
    unsigned short h0s, l0s, h1s, l1s;
    split_tr(xv0[0], h0s, l0s); split_tr(xv0[1], h1s, l1s);
    ushort2v hh = {h0s, h1s}, ll = {l0s, l1s};
    *(ushort2v*)&s.xq[0][sts][srow][sfp * 2] = hh;
    *(ushort2v*)&s.xq[0][sts][srow + 8][sfp * 2] = ll;
    *(ushort2v*)&s.xq[0][sts][srow + 8][8 + sfp * 2] = hh;
  }

  // Wout fragments: N-cols 0..7 = Wout_hi, 8..15 = Wout_lo
  bf16x8 Bw[4];
#pragma unroll
  for (int kt = 0; kt < 4; ++kt) {
    bf16x8 bw;
#pragma unroll
    for (int j = 0; j < 8; ++j) {
      unsigned short hv, lv; split_tr(Wout[(kt * 32 + q * 8 + j) * F + (n & 7)], hv, lv);
      bw[j] = (short)((n < 8) ? hv : lv);
    }
    Bw[kt] = bw;
  }
  const float boutr = boutg[n & 7];
  float cst[2] = {0.f, 0.f};
  __syncthreads();

  // Convention probe: 0 on lanes whose pair_fold returns the 1st-operand
  // fold, 2 on lanes that get the 2nd-operand fold == this lane's row offset.
  const float probe = pair_fold(0.0f, 1.0f);
  const int r0 = ((lane & 31) >> 4) * 4 + (int)probe;
  const int cc = w * 16 + n;

  bf16x8 A[4], Ax;
  {
    bf16x8 zz = {0, 0, 0, 0, 0, 0, 0, 0};
#pragma unroll
    for (int kt = 0; kt < 4; ++kt) A[kt] = zz;
    Ax = zz;
  }

  bf16x8 B1[5][4];
  f32x4 bias4[4];
  const f32x4 zero4 = {0.f, 0.f, 0.f, 0.f};

  // ---- weight preload (per phase) ----
  auto preload = [&](const float* U, const float* W, const float* bi) {
#pragma unroll
    for (int kt = 0; kt < 5; ++kt)
#pragma unroll
      for (int g = 0; g < 4; ++g) {
        const int col = g * 128 + w * 16 + n;
        bf16x8 b1;
#pragma unroll
        for (int j = 0; j < 8; ++j) {
          unsigned short v = 0;
          if (kt < 4) {
            v = bf_rtn(U[(kt * 32 + q * 8 + j) * G4 + col]);
          } else {
            const int kk = q * 8 + j;
            unsigned short hv, lv;
            if (kk < 8)       { split_tr(W[kk * G4 + col], hv, lv); v = hv; }
            else if (kk < 16) { split_tr(W[(kk - 8) * G4 + col], hv, lv); v = lv; }
          }
          b1[j] = (short)v;
        }
        B1[kt][g] = b1;
      }
#pragma unroll
    for (int g = 0; g < 4; ++g) {
      const float b = 0.5f * bi[g * 128 + w * 16 + n];
      bias4[g] = f32x4{b, b, b, b};
    }
  };

  // ---- per-step core: MFMA pass + fold + LSTM cell + h write ----
  auto lstm_core = [&](int pnxt) {
    f32x4 acc[4];
#pragma unroll
    for (int g = 0; g < 4; ++g)
      acc[g] = __builtin_amdgcn_mfma_f32_16x16x32_bf16(A[0], B1[0][g], bias4[g], 0, 0, 0);
#pragma unroll
    for (int kt = 1; kt < 4; ++kt)
#pragma unroll
      for (int g = 0; g < 4; ++g)
        acc[g] = __builtin_amdgcn_mfma_f32_16x16x32_bf16(A[kt], B1[kt][g], acc[g], 0, 0, 0);
#pragma unroll
    for (int g = 0; g < 4; ++g)
      acc[g] = __builtin_amdgcn_mfma_f32_16x16x32_bf16(Ax, B1[4][g], acc[g], 0, 0, 0);

    // zA/zB are rows r0 / r0+1 (probe-consistent on both lane halves)
    float zA[4], zB[4];
#pragma unroll
    for (int g = 0; g < 4; ++g) {
      zA[g] = pair_fold(acc[g][0], acc[g][2]);
      zB[g] = pair_fold(acc[g][1], acc[g][3]);
    }
    cst[0] = sigm(zA[1]) * cst[0] + sigm(zA[0]) * tanh_(zA[2]);
    cst[1] = sigm(zB[1]) * cst[1] + sigm(zB[0]) * tanh_(zB[2]);
    const float h0 = sigm(zA[3]) * tanh_(cst[0]);
    const float h1 = sigm(zB[3]) * tanh_(cst[1]);
    unsigned short hv0, lv0, hv1, lv1;
    split_tr(h0, hv0, lv0); split_tr(h1, hv1, lv1);
    s.hb[pnxt][r0][cc]     = hv0;  s.hb[pnxt][r0 + 8][cc] = lv0;
    s.hb[pnxt][r0 + 1][cc] = hv1;  s.hb[pnxt][r0 + 9][cc] = lv1;
  };

  // =================== ENCODER ===================
  preload(Uenc, Wenc, benc);

  float2v xv = {0.f, 0.f};  // in-flight next-chunk x (held ACROSS steps!)

  for (int t = 0; t < T; ++t) {
    const int pnxt = (t & 1) ^ 1;

    Ax = *(const bf16x8*)&s.xq[(t >> 4) & 1][t & (CS - 1)][n][q * 8];

    const bool do_load  = (((t + 2) & (CS - 1)) == 0) && (t + 2 < T);
    const bool do_write = (((t + 1) & (CS - 1)) == 0) && (t + 1 < T);
    if (do_load) xv = *(const float2v*)&x[xsb + (long)(t + 2) * F];

    lstm_core(pnxt);

    if (do_write) {
      const int cb = ((t + 1) >> 4) & 1;
      unsigned short h0s, l0s, h1s, l1s;
      split_tr(xv[0], h0s, l0s); split_tr(xv[1], h1s, l1s);
      ushort2v hh = {h0s, h1s}, ll = {l0s, l1s};
      *(ushort2v*)&s.xq[cb][sts][srow][sfp * 2] = hh;
      *(ushort2v*)&s.xq[cb][sts][srow + 8][sfp * 2] = ll;
      *(ushort2v*)&s.xq[cb][sts][srow + 8][8 + sfp * 2] = hh;
    }

    bar_lgkm();

#pragma unroll
    for (int kt = 0; kt < 4; ++kt)
      A[kt] = *(const bf16x8*)&s.hb[pnxt][n][kt * 32 + q * 8];
  }

  // =================== DECODER ===================
  preload(Udec, Wdec, bdec);

  if (tid < 64) {  // stage y_{-1} = x[:,T-1,:] into parity slot 0
    unsigned short hv, lv;
    split_tr(x[(gb + (tid >> 3)) * (long)(T * F) + (T - 1) * F + (tid & 7)], hv, lv);
    s.xp[0][tid >> 3][tid & 7] = hv;
    s.xp[0][(tid >> 3) + 8][tid & 7] = lv;
    s.xp[0][(tid >> 3) + 8][(tid & 7) + 8] = hv;
  }
  __syncthreads();

  // per-lane output row pointers (rows r0 and r0+1, col n; valid for n<8)
  float* o0 = out + ((gb + r0) * (long)T) * F + n;
  float* o1 = o0 + (long)T * F;

  for (int t = 0; t < T; ++t) {
    const int pcur = t & 1, pnxt = pcur ^ 1;

    Ax = *(const bf16x8*)&s.xp[pcur][n][q * 8];

    lstm_core(pnxt);

    bar_lgkm();

#pragma unroll
    for (int kt = 0; kt < 4; ++kt)
      A[kt] = *(const bf16x8*)&s.hb[pnxt][n][kt * 32 + q * 8];

    // dense y = relu(h@Wout + b), redundant per wave (idempotent feedback)
    f32x4 ay = __builtin_amdgcn_mfma_f32_16x16x32_bf16(A[0], Bw[0], zero4, 0, 0, 0);
#pragma unroll
    for (int kt = 1; kt < 4; ++kt)
      ay = __builtin_amdgcn_mfma_f32_16x16x32_bf16(A[kt], Bw[kt], ay, 0, 0, 0);
    float s8[4];
#pragma unroll
    for (int p = 0; p < 4; ++p)
      s8[p] = ay[p] + __shfl_xor(ay[p], 8, 64);             // + h@Wout_lo
    const float y0 = fmaxf(pair_fold(s8[0], s8[2]) + boutr, 0.f);  // row r0
    const float y1 = fmaxf(pair_fold(s8[1], s8[3]) + boutr, 0.f);  // row r0+1
    if (n < 8) {
      if (w == 0) { o0[t * F] = y0; o1[t * F] = y1; }
      unsigned short hv, lv;
      split_tr(y0, hv, lv);
      s.xp[pnxt][r0][n]         = hv;
      s.xp[pnxt][r0 + 8][n]     = lv;
      s.xp[pnxt][r0 + 8][n + 8] = hv;
      split_tr(y1, hv, lv);
      s.xp[pnxt][r0 + 1][n]         = hv;
      s.xp[pnxt][r0 + 9][n]         = lv;
      s.xp[pnxt][r0 + 9][n + 8]     = hv;
    }
  }
}

} // namespace

extern "C" void kernel_launch(void* const* d_in, const int* in_sizes, int n_in,
                              void* d_out, int out_size, void* d_ws, size_t ws_size,
                              hipStream_t stream) {
  const float* x    = (const float*)d_in[0];
  const float* Wenc = (const float*)d_in[1];
  const float* Uenc = (const float*)d_in[2];
  const float* benc = (const float*)d_in[3];
  const float* Wdec = (const float*)d_in[4];
  const float* Udec = (const float*)d_in[5];
  const float* bdec = (const float*)d_in[6];
  const float* Wout = (const float*)d_in[7];
  const float* bout = (const float*)d_in[8];
  float* out = (float*)d_out;

  const int Bsz = in_sizes[0] / (T * F);  // 2048
  const int nblocks = Bsz / 8;            // 256
  rae_v7b<<<dim3(nblocks), dim3(NTH), 0, stream>>>(
      x, Wenc, Uenc, benc, Wdec, Udec, bdec, Wout, bout, out);
}

// Round 5
// 992.598 us; speedup vs baseline: 1.3927x; 1.0669x over previous
//
#include <hip/hip_runtime.h>

// RegressiveAutoEncoder B=2048,T=512,F=8,H=128 — MFMA v8 (pipeline rotation).
// v7b measured 1073us: VALU 52% + MFMA 30% at 2 waves/SIMD, ~18% stall.
// MFMA and VALU are separate pipes -> overlap them within the wave:
//  (1) DECODER ROTATION: per step, after barrier+A-read, issue dense (4 MFMA)
//      then next-step h-partial hacc = bias + sum A[kt]B1[kt] (16 MFMA,
//      depends only on h_t, NOT y_t). The y epilogue (fold/relu/split/
//      xp writes) runs on VALU under the MFMA issue. Loop top then only
//      finishes: acc = hacc + Ax*B1[4] (4 MFMA).
//  (2) ENCODER Ax-FIRST: chain starts with the x-term (pre-staged, readable
//      right after barrier); Ax ds_read issued before A reads -> first MFMA
//      waits lgkmcnt(4), hiding most of the A-read latency.
//  (3) y epilogue: fold32 and shfl8 commute -> pf first, one sh8 (16->12 ops)
//  (4) #pragma unroll 2: parity-dependent LDS addressing loop-invariant
// Kept from v7b: lgkm-only barrier, XS=40 padded rows, 16-step x chunks
// (load@t+2 / write@t+1, xv held across steps), probe-based pair_fold row
// assignment, bias-as-C-operand, rtn-bf16 U, 3-term x/y rows, 0.5x bias.
// Bank conflicts 4.2e7 = structural b128 8-lane/group minimum; not a lever.

namespace {

typedef __attribute__((ext_vector_type(8))) short bf16x8;
typedef __attribute__((ext_vector_type(4))) float f32x4;
typedef __attribute__((ext_vector_type(2))) unsigned int uint2v;
typedef __attribute__((ext_vector_type(4))) unsigned int uint4v;
typedef __attribute__((ext_vector_type(2))) unsigned short ushort2v;
typedef __attribute__((ext_vector_type(2))) float float2v;

constexpr int T = 512, F = 8, H = 128, G4 = 512, NTH = 512;
constexpr int HS = 136;  // hb row stride in shorts (272B, b128-aligned)
constexpr int XS = 40;   // xp/xq row stride in shorts (80B)
constexpr int CS = 16;   // encoder x chunk length (timesteps)

struct __align__(16) Smem {
  unsigned short hb[2][16][HS];      // rows 0..7 h_hi, 8..15 h_lo; dbuf by parity
  unsigned short xp[2][16][XS];      // decoder feedback y; dbuf by parity
  unsigned short xq[2][CS][16][XS];  // encoder pre-split x chunks; dbuf by chunk
};

__device__ __forceinline__ float rcpf(float v) { return __builtin_amdgcn_rcpf(v); }
__device__ __forceinline__ float sigm(float v) { return rcpf(1.0f + __expf(-v)); }
__device__ __forceinline__ float tanh_(float v) { return 1.0f - 2.0f * rcpf(__expf(2.0f * v) + 1.0f); }

__device__ __forceinline__ unsigned short bf_rtn(float v) {
  unsigned u = __float_as_uint(v);
  return (unsigned short)((u + 0x7FFFu + ((u >> 16) & 1u)) >> 16);
}
__device__ __forceinline__ void split_tr(float v, unsigned short& hi, unsigned short& lo) {
  unsigned u = __float_as_uint(v);
  hi = (unsigned short)(u >> 16);
  lo = bf_rtn(v - __uint_as_float(u & 0xFFFF0000u));
}

// Pair-fold: one half-wave gets fold32(a)=a[l]+a[l^32], the other fold32(b);
// which half gets which is probed once and baked into r0.
__device__ __forceinline__ float pair_fold(float a, float b) {
  uint2v r = __builtin_amdgcn_permlane32_swap(__float_as_uint(a), __float_as_uint(b), false, false);
  return __uint_as_float(r[0]) + __uint_as_float(r[1]);
}

// Barrier draining only LDS (lgkm); outstanding global ops not drained.
__device__ __forceinline__ void bar_lgkm() {
  __asm__ __volatile__("s_waitcnt lgkmcnt(0)" ::: "memory");
  __builtin_amdgcn_s_barrier();
  __asm__ __volatile__("" ::: "memory");
}

__global__ __launch_bounds__(NTH, 2)
void rae_v8(const float* __restrict__ x,
            const float* __restrict__ Wenc, const float* __restrict__ Uenc, const float* __restrict__ benc,
            const float* __restrict__ Wdec, const float* __restrict__ Udec, const float* __restrict__ bdec,
            const float* __restrict__ Wout, const float* __restrict__ boutg,
            float* __restrict__ out)
{
  __shared__ Smem s;
  const int tid = threadIdx.x, lane = tid & 63, w = tid >> 6;
  const int q = lane >> 4, n = lane & 15;
  const long gb = (long)blockIdx.x * 8;

  {  // vectorized zero of all LDS (zeros double as the K-padding regions)
    uint4v z4 = {0u, 0u, 0u, 0u};
#pragma unroll 4
    for (int i = tid; i < (int)(sizeof(Smem) / 16); i += NTH)
      ((uint4v*)&s)[i] = z4;
  }
  __syncthreads();  // zero pass must complete before any staging

  // encoder x staging: 512 thr = 16 steps x 8 rows x 4 float2.
  const int sfp = tid & 3, srow = (tid >> 2) & 7, sts = tid >> 5;
  const long xsb = (gb + srow) * (long)(T * F) + sts * F + sfp * 2;

  {  // stage chunk 0 (steps 0..15)
    float2v xv0 = *(const float2v*)&x[xsb];
    unsigned short h0s, l0s, h1s, l1s;
    split_tr(xv0[0], h0s, l0s); split_tr(xv0[1], h1s, l1s);
    ushort2v hh = {h0s, h1s}, ll = {l0s, l1s};
    *(ushort2v*)&s.xq[0][sts][srow][sfp * 2] = hh;
    *(ushort2v*)&s.xq[0][sts][srow + 8][sfp * 2] = ll;
    *(ushort2v*)&s.xq[0][sts][srow + 8][8 + sfp * 2] = hh;
  }

  // Wout fragments: N-cols 0..7 = Wout_hi, 8..15 = Wout_lo
  bf16x8 Bw[4];
#pragma unroll
  for (int kt = 0; kt < 4; ++kt) {
    bf16x8 bw;
#pragma unroll
    for (int j = 0; j < 8; ++j) {
      unsigned short hv, lv; split_tr(Wout[(kt * 32 + q * 8 + j) * F + (n & 7)], hv, lv);
      bw[j] = (short)((n < 8) ? hv : lv);
    }
    Bw[kt] = bw;
  }
  const float boutr = boutg[n & 7];
  float cst[2] = {0.f, 0.f};
  __syncthreads();

  // Convention probe -> row offset owned by this lane's pair_fold outputs.
  const float probe = pair_fold(0.0f, 1.0f);
  const int r0 = ((lane & 31) >> 4) * 4 + (int)probe;
  const int cc = w * 16 + n;

  bf16x8 A[4], Ax;
  {
    bf16x8 zz = {0, 0, 0, 0, 0, 0, 0, 0};
#pragma unroll
    for (int kt = 0; kt < 4; ++kt) A[kt] = zz;
    Ax = zz;
  }

  bf16x8 B1[5][4];
  f32x4 bias4[4];
  const f32x4 zero4 = {0.f, 0.f, 0.f, 0.f};

  // ---- weight preload (per phase) ----
  auto preload = [&](const float* U, const float* W, const float* bi) {
#pragma unroll
    for (int kt = 0; kt < 5; ++kt)
#pragma unroll
      for (int g = 0; g < 4; ++g) {
        const int col = g * 128 + w * 16 + n;
        bf16x8 b1;
#pragma unroll
        for (int j = 0; j < 8; ++j) {
          unsigned short v = 0;
          if (kt < 4) {
            v = bf_rtn(U[(kt * 32 + q * 8 + j) * G4 + col]);
          } else {
            const int kk = q * 8 + j;
            unsigned short hv, lv;
            if (kk < 8)       { split_tr(W[kk * G4 + col], hv, lv); v = hv; }
            else if (kk < 16) { split_tr(W[(kk - 8) * G4 + col], hv, lv); v = lv; }
          }
          b1[j] = (short)v;
        }
        B1[kt][g] = b1;
      }
#pragma unroll
    for (int g = 0; g < 4; ++g) {
      const float b = 0.5f * bi[g * 128 + w * 16 + n];
      bias4[g] = f32x4{b, b, b, b};
    }
  };

  // ---- fold + LSTM cell + h store (shared by enc/dec) ----
  auto activ_store = [&](f32x4 (&acc)[4], int slot) {
    float zA[4], zB[4];
#pragma unroll
    for (int g = 0; g < 4; ++g) {
      zA[g] = pair_fold(acc[g][0], acc[g][2]);
      zB[g] = pair_fold(acc[g][1], acc[g][3]);
    }
    cst[0] = sigm(zA[1]) * cst[0] + sigm(zA[0]) * tanh_(zA[2]);
    cst[1] = sigm(zB[1]) * cst[1] + sigm(zB[0]) * tanh_(zB[2]);
    const float h0 = sigm(zA[3]) * tanh_(cst[0]);
    const float h1 = sigm(zB[3]) * tanh_(cst[1]);
    unsigned short hv0, lv0, hv1, lv1;
    split_tr(h0, hv0, lv0); split_tr(h1, hv1, lv1);
    s.hb[slot][r0][cc]     = hv0;  s.hb[slot][r0 + 8][cc] = lv0;
    s.hb[slot][r0 + 1][cc] = hv1;  s.hb[slot][r0 + 9][cc] = lv1;
  };

  // =================== ENCODER ===================
  preload(Uenc, Wenc, benc);

  // prologue: h_{-1}=0 (A already zero); Ax = x_0 (chunk 0 staged + synced)
  Ax = *(const bf16x8*)&s.xq[0][0][n][q * 8];

  float2v xv = {0.f, 0.f};  // in-flight next-chunk x (held ACROSS steps)

#pragma unroll 2
  for (int t = 0; t < T; ++t) {
    const int pnxt = (t & 1) ^ 1;
    const bool do_load  = (((t + 2) & (CS - 1)) == 0) && (t + 2 < T);
    const bool do_write = (((t + 1) & (CS - 1)) == 0) && (t + 1 < T);
    if (do_load) xv = *(const float2v*)&x[xsb + (long)(t + 2) * F];

    // chain starts with the x-term (Ax ready immediately post-barrier)
    f32x4 acc[4];
#pragma unroll
    for (int g = 0; g < 4; ++g)
      acc[g] = __builtin_amdgcn_mfma_f32_16x16x32_bf16(Ax, B1[4][g], bias4[g], 0, 0, 0);
#pragma unroll
    for (int kt = 0; kt < 4; ++kt)
#pragma unroll
      for (int g = 0; g < 4; ++g)
        acc[g] = __builtin_amdgcn_mfma_f32_16x16x32_bf16(A[kt], B1[kt][g], acc[g], 0, 0, 0);

    activ_store(acc, pnxt);

    if (do_write) {
      const int cb = ((t + 1) >> 4) & 1;
      unsigned short h0s, l0s, h1s, l1s;
      split_tr(xv[0], h0s, l0s); split_tr(xv[1], h1s, l1s);
      ushort2v hh = {h0s, h1s}, ll = {l0s, l1s};
      *(ushort2v*)&s.xq[cb][sts][srow][sfp * 2] = hh;
      *(ushort2v*)&s.xq[cb][sts][srow + 8][sfp * 2] = ll;
      *(ushort2v*)&s.xq[cb][sts][srow + 8][8 + sfp * 2] = hh;
    }

    bar_lgkm();

    // reads for step t+1: Ax FIRST (first MFMA next iter waits lgkmcnt(4))
    const int tn = t + 1;  // tn==T reads stale chunk-0 word: harmless, unused
    Ax = *(const bf16x8*)&s.xq[(tn >> 4) & 1][tn & (CS - 1)][n][q * 8];
#pragma unroll
    for (int kt = 0; kt < 4; ++kt)
      A[kt] = *(const bf16x8*)&s.hb[pnxt][n][kt * 32 + q * 8];
  }

  // =================== DECODER (rotated) ===================
  preload(Udec, Wdec, bdec);

  if (tid < 64) {  // stage y_{-1} = x[:,T-1,:] into xp[1] (slot (0-1)&1)
    unsigned short hv, lv;
    split_tr(x[(gb + (tid >> 3)) * (long)(T * F) + (T - 1) * F + (tid & 7)], hv, lv);
    s.xp[1][tid >> 3][tid & 7] = hv;
    s.xp[1][(tid >> 3) + 8][tid & 7] = lv;
    s.xp[1][(tid >> 3) + 8][(tid & 7) + 8] = hv;
  }
  __syncthreads();

  // prologue: A still holds h_enc (encoder's final bottom-read of hb[0]).
  // hacc = bias + sum A[kt]B1[kt]; Ax = y_{-1}.
  f32x4 hacc[4];
#pragma unroll
  for (int g = 0; g < 4; ++g)
    hacc[g] = __builtin_amdgcn_mfma_f32_16x16x32_bf16(A[0], B1[0][g], bias4[g], 0, 0, 0);
#pragma unroll
  for (int kt = 1; kt < 4; ++kt)
#pragma unroll
    for (int g = 0; g < 4; ++g)
      hacc[g] = __builtin_amdgcn_mfma_f32_16x16x32_bf16(A[kt], B1[kt][g], hacc[g], 0, 0, 0);
  Ax = *(const bf16x8*)&s.xp[1][n][q * 8];

  // per-lane output row pointers (rows r0 and r0+1, col n; valid for n<8)
  float* o0 = out + ((gb + r0) * (long)T) * F + n;
  float* o1 = o0 + (long)T * F;

#pragma unroll 2
  for (int t = 0; t < T; ++t) {
    const int wA = (t & 1) ^ 1;  // hb slot for h_t

    // finish LSTM: acc = hacc + Ax*B1[4]  (4 MFMA)
    f32x4 acc[4];
#pragma unroll
    for (int g = 0; g < 4; ++g)
      acc[g] = __builtin_amdgcn_mfma_f32_16x16x32_bf16(Ax, B1[4][g], hacc[g], 0, 0, 0);

    activ_store(acc, wA);

    bar_lgkm();

#pragma unroll
    for (int kt = 0; kt < 4; ++kt)
      A[kt] = *(const bf16x8*)&s.hb[wA][n][kt * 32 + q * 8];

    // dense first (y_t on the feedback critical path) ...
    f32x4 ay = __builtin_amdgcn_mfma_f32_16x16x32_bf16(A[0], Bw[0], zero4, 0, 0, 0);
#pragma unroll
    for (int kt = 1; kt < 4; ++kt)
      ay = __builtin_amdgcn_mfma_f32_16x16x32_bf16(A[kt], Bw[kt], ay, 0, 0, 0);

    // ... then next-step h-partial (16 MFMA, independent of y_t) issues
    // while the y epilogue below runs on VALU.
#pragma unroll
    for (int g = 0; g < 4; ++g)
      hacc[g] = __builtin_amdgcn_mfma_f32_16x16x32_bf16(A[0], B1[0][g], bias4[g], 0, 0, 0);
#pragma unroll
    for (int kt = 1; kt < 4; ++kt)
#pragma unroll
      for (int g = 0; g < 4; ++g)
        hacc[g] = __builtin_amdgcn_mfma_f32_16x16x32_bf16(A[kt], B1[kt][g], hacc[g], 0, 0, 0);

    // y epilogue: fold32 and shfl8 commute -> pf first, single sh8 each
    const float sA = pair_fold(ay[0], ay[2]);
    const float sB = pair_fold(ay[1], ay[3]);
    const float y0 = fmaxf(sA + __shfl_xor(sA, 8, 64) + boutr, 0.f);  // row r0
    const float y1 = fmaxf(sB + __shfl_xor(sB, 8, 64) + boutr, 0.f);  // row r0+1
    if (n < 8) {
      if (w == 0) { o0[t * F] = y0; o1[t * F] = y1; }
      unsigned short hv, lv;
      split_tr(y0, hv, lv);
      s.xp[t & 1][r0][n]         = hv;
      s.xp[t & 1][r0 + 8][n]     = lv;
      s.xp[t & 1][r0 + 8][n + 8] = hv;
      split_tr(y1, hv, lv);
      s.xp[t & 1][r0 + 1][n]     = hv;
      s.xp[t & 1][r0 + 9][n]     = lv;
      s.xp[t & 1][r0 + 9][n + 8] = hv;
    }
    // own-wave readback (same-wave DS ordering; proven pattern since v5)
    Ax = *(const bf16x8*)&s.xp[t & 1][n][q * 8];
  }
}

} // namespace

extern "C" void kernel_launch(void* const* d_in, const int* in_sizes, int n_in,
                              void* d_out, int out_size, void* d_ws, size_t ws_size,
                              hipStream_t stream) {
  const float* x    = (const float*)d_in[0];
  const float* Wenc = (const float*)d_in[1];
  const float* Uenc = (const float*)d_in[2];
  const float* benc = (const float*)d_in[3];
  const float* Wdec = (const float*)d_in[4];
  const float* Udec = (const float*)d_in[5];
  const float* bdec = (const float*)d_in[6];
  const float* Wout = (const float*)d_in[7];
  const float* bout = (const float*)d_in[8];
  float* out = (float*)d_out;

  const int Bsz = in_sizes[0] / (T * F);  // 2048
  const int nblocks = Bsz / 8;            // 256
  rae_v8<<<dim3(nblocks), dim3(NTH), 0, stream>>>(
      x, Wenc, Uenc, benc, Wdec, Udec, bdec, Wout, bout, out);
}